// Round 12
// baseline (1123.063 us; speedup 1.0000x reference)
//
#include <hip/hip_runtime.h>
#include <hip/hip_bf16.h>

#define NN 50000
#define NE 600000
#define NP 500000
#define DH 128
#define NRBF 16
#define NL 3

typedef __attribute__((ext_vector_type(8))) short bf16x8;
typedef __attribute__((ext_vector_type(4))) float f32x4;

__device__ __forceinline__ unsigned short f2b(float f){
  unsigned int u = __float_as_uint(f);
  u += 0x7fffu + ((u >> 16) & 1u);
  return (unsigned short)(u >> 16);
}
__device__ __forceinline__ float b2f(unsigned short u){
  return __uint_as_float(((unsigned)u) << 16);
}

__device__ __forceinline__ void zero_acc(f32x4 (&acc)[4][2]){
#pragma unroll
  for (int i=0;i<4;i++)
#pragma unroll
    for (int j=0;j<2;j++)
#pragma unroll
      for (int r=0;r<4;r++) acc[i][j][r]=0.f;
}

// Swizzled-LDS GEMM: X rows are RSB bytes (pow2), byte-in-row XOR'ed with
// ((row&7)<<4) (T2). Bp: packed weights [ct(8)][kb(KB)][lane(64)][e(8)] bf16.
template<int RSB, int KB>
__device__ __forceinline__ void gemm_sw(const short* X, const short* __restrict__ Bp,
                                        int t, f32x4 (&acc)[4][2]){
  const int lane=t&63, w=t>>6, m=lane&15, g=lane>>4;
  const char* Xc = (const char*)X;
#pragma unroll
  for (int kb=0; kb<KB; kb++){
    bf16x8 a[4];
#pragma unroll
    for (int rt=0; rt<4; rt++){
      int ar = rt*16 + m;
      a[rt] = *reinterpret_cast<const bf16x8*>(Xc + ar*RSB + ((kb*64 + g*16) ^ ((ar&7)<<4)));
    }
#pragma unroll
    for (int c=0;c<2;c++){
      bf16x8 b = *reinterpret_cast<const bf16x8*>(Bp + ((size_t)((w*2+c)*KB+kb)*64 + lane)*8);
#pragma unroll
      for (int rt=0; rt<4; rt++)
        acc[rt][c] = __builtin_amdgcn_mfma_f32_16x16x32_bf16(a[rt], b, acc[rt][c], 0,0,0);
    }
  }
}

// Pack W (Kr x 128 row-major fp32, zero-padded to KB*32 rows) into B-frag layout.
__global__ void pack_w_kernel(const float* __restrict__ W0, int Kr, int KB,
                              long wStride, long oStride, short* __restrict__ out0){
  int l = blockIdx.y;
  const float* W = W0 + (size_t)l*wStride;
  short* out = out0 + (size_t)l*oStride;
  int idx = blockIdx.x*256 + threadIdx.x;
  int total = 8*KB*64;
  if (idx >= total) return;
  int lane = idx & 63;
  int kb = (idx>>6) % KB;
  int ct = (idx>>6) / KB;
  int col = ct*16 + (lane&15);
  int k0 = kb*32 + 8*(lane>>4);
  bf16x8 pv;
#pragma unroll
  for (int e=0;e<8;e++){
    int k = k0+e;
    float f = (k<Kr) ? W[(size_t)k*DH + col] : 0.f;
    pv[e] = (short)f2b(f);
  }
  *reinterpret_cast<bf16x8*>(out + (size_t)idx*8) = pv;
}

// ---------- counting sort machinery ----------
__global__ void hist_kernel(const int* __restrict__ keys, int stride, int n,
                            int* __restrict__ cnt){
  int e = blockIdx.x*256 + threadIdx.x;
  if (e < n) atomicAdd(&cnt[keys[(size_t)e*stride]], 1);
}

__global__ void scan_kernel(const int* __restrict__ cnt, int total, int* __restrict__ rowptr){
  __shared__ int parts[1024];
  const int t = threadIdx.x;
  const int CH = (NN + 1023)/1024;  // 49
  int base = t*CH;
  int s = 0;
  for (int i=0;i<CH;i++){ int j=base+i; if (j<NN) s += cnt[j]; }
  parts[t] = s; __syncthreads();
  for (int off=1; off<1024; off<<=1){
    int v = (t>=off) ? parts[t-off] : 0;
    __syncthreads();
    parts[t] += v;
    __syncthreads();
  }
  int ex = (t==0) ? 0 : parts[t-1];
  for (int i=0;i<CH;i++){
    int j=base+i;
    if (j<NN){ rowptr[j] = ex; ex += cnt[j]; }
  }
  if (t==0) rowptr[NN] = total;
}

__global__ void scatter_kernel(const int* __restrict__ srcI, const int* __restrict__ dstI,
                               int* __restrict__ ofs, int* __restrict__ ssrc,
                               int* __restrict__ sdst){
  int e = blockIdx.x*256 + threadIdx.x;
  if (e >= NE) return;
  int d = dstI[e];
  int p = atomicAdd(&ofs[d], 1);
  ssrc[p] = srcI[e];
  sdst[p] = d;
}

// sort pairs by u; keep original index for scattered output write
__global__ void pair_scatter_kernel(const int* __restrict__ pairs, int* __restrict__ ofs,
                                    int* __restrict__ su, int* __restrict__ sv,
                                    int* __restrict__ sidx){
  int p = blockIdx.x*256 + threadIdx.x;
  if (p >= NP) return;
  int u = pairs[2*p], v = pairs[2*p+1];
  int pos = atomicAdd(&ofs[u], 1);
  su[pos] = u; sv[pos] = v; sidx[pos] = p;
}

__global__ void rbf_kernel(const float* __restrict__ coords, const int* __restrict__ srcI,
                           const int* __restrict__ dstI, short* __restrict__ rbfp){
  int e = blockIdx.x*256 + threadIdx.x;
  if (e >= NE) return;
  int s = srcI[e], d = dstI[e];
  float dx = coords[2*s]-coords[2*d];
  float dy = coords[2*s+1]-coords[2*d+1];
  float r = sqrtf(dx*dx + dy*dy + 1e-8f);
  bf16x8 v0, v1;
#pragma unroll
  for (int i=0;i<8;i++){
    float t0 = (r - 0.1f*i)*10.f;
    v0[i] = (short)f2b(expf(-t0*t0));
    float t1 = (r - 0.1f*(i+8))*10.f;
    v1[i] = (short)f2b(expf(-t1*t1));
  }
  *reinterpret_cast<bf16x8*>(rbfp + (size_t)e*NRBF) = v0;
  *reinterpret_cast<bf16x8*>(rbfp + (size_t)e*NRBF + 8) = v1;
}

// Node MLP: y1 = relu(coords@W1+b1) scalar (K=2), then 128x128 GEMM via MFMA.
__global__ __launch_bounds__(256, 2) void node_kernel(
    const float* __restrict__ coords, const float* __restrict__ W1, const float* __restrict__ b1,
    const short* __restrict__ W2p, const float* __restrict__ b2,
    float* __restrict__ h, short* __restrict__ hbf)
{
  __shared__ __align__(16) short X[64*128];
  const int t = threadIdx.x;
  const int n0 = blockIdx.x*64;
  {
    int row = t >> 2;
    int n = n0 + row;
    float c0=0.f, c1=0.f;
    if (n < NN){ c0 = coords[2*n]; c1 = coords[2*n+1]; }
    char* Xc = (char*)X;
#pragma unroll
    for (int i=0;i<32;i++){
      int col = (t&3)*32 + i;
      float y = fmaxf(c0*W1[col] + c1*W1[DH+col] + b1[col], 0.f);
      *reinterpret_cast<short*>(Xc + row*256 + ((col*2) ^ ((row&7)<<4))) = (short)f2b(y);
    }
  }
  __syncthreads();
  f32x4 acc[4][2]; zero_acc(acc);
  gemm_sw<256,4>(X, W2p, t, acc);
  const int lane=t&63, w=t>>6, m=lane&15, g=lane>>4;
  float b2v0=b2[w*32+m], b2v1=b2[w*32+16+m];
#pragma unroll
  for (int rt=0;rt<4;rt++){
#pragma unroll
    for (int c=0;c<2;c++){
      float bb = c? b2v1 : b2v0;
      int col = (w*2+c)*16 + m;
#pragma unroll
      for (int r=0;r<4;r++){
        int row = rt*16 + g*4 + r;
        int n = n0 + row;
        if (n < NN){
          float val = acc[rt][c][r] + bb;
          h[(size_t)n*DH + col] = val;
          hbf[(size_t)n*DH + col] = (short)f2b(val);
        }
      }
    }
  }
}

// Dual 128x128 GEMM on hbf rows: outA = hbf@WpA (+biasA), outB = hbf@WpB. fp32 outs.
__global__ __launch_bounds__(256, 2) void nodegemm2_f32(
    const short* __restrict__ hbf,
    const short* __restrict__ WpA, const float* __restrict__ biasA, float* __restrict__ outA,
    const short* __restrict__ WpB, float* __restrict__ outB)
{
  const int t=threadIdx.x, lane=t&63, w=t>>6, m=lane&15, g=lane>>4;
  const int n0 = blockIdx.x*64;
  f32x4 accA[4][2], accB[4][2]; zero_acc(accA); zero_acc(accB);
#pragma unroll
  for (int kb=0;kb<4;kb++){
    bf16x8 a[4];
#pragma unroll
    for (int rt=0;rt<4;rt++){
      int n = n0 + rt*16 + m; if (n >= NN) n = NN-1;
      a[rt] = *reinterpret_cast<const bf16x8*>(hbf + (size_t)n*DH + kb*32 + g*8);
    }
#pragma unroll
    for (int c=0;c<2;c++){
      bf16x8 bA = *reinterpret_cast<const bf16x8*>(WpA + ((size_t)((w*2+c)*4+kb)*64 + lane)*8);
      bf16x8 bB = *reinterpret_cast<const bf16x8*>(WpB + ((size_t)((w*2+c)*4+kb)*64 + lane)*8);
#pragma unroll
      for (int rt=0;rt<4;rt++){
        accA[rt][c] = __builtin_amdgcn_mfma_f32_16x16x32_bf16(a[rt], bA, accA[rt][c], 0,0,0);
        accB[rt][c] = __builtin_amdgcn_mfma_f32_16x16x32_bf16(a[rt], bB, accB[rt][c], 0,0,0);
      }
    }
  }
#pragma unroll
  for (int rt=0;rt<4;rt++){
#pragma unroll
    for (int c=0;c<2;c++){
      int col = (w*2+c)*16 + m;
      float bb = biasA ? biasA[col] : 0.f;
#pragma unroll
      for (int r=0;r<4;r++){
        int n = n0 + rt*16 + g*4 + r;
        if (n < NN){
          outA[(size_t)n*DH + col] = accA[rt][c][r] + bb;
          outB[(size_t)n*DH + col] = accB[rt][c][r];
        }
      }
    }
  }
}

// Message on dst-sorted edges: y = relu(hA[src]+hB[dst]+rbf@W1c), m = y@W2+b2.
// m stored bf16 back into X (17 KB LDS total -> high occupancy), then in-tile
// segmented reduction over sorted dst runs -> few fp32 atomics into agg.
__global__ __launch_bounds__(256, 6) void msg_kernel(
    const float* __restrict__ hA, const float* __restrict__ hB,
    const short* __restrict__ rbfp,
    const int* __restrict__ ssrc, const int* __restrict__ sdst,
    const short* __restrict__ W1cp, const short* __restrict__ W2p,
    const float* __restrict__ b2, float* __restrict__ agg)
{
  __shared__ __align__(16) short X[64*128];   // 16 KB swizzled, reused Y -> m
  __shared__ int srcl[64], dstl[64];
  const int t=threadIdx.x, lane=t&63, w=t>>6, m=lane&15, g=lane>>4;
  const int e0 = blockIdx.x*64;
  if (t < 64) srcl[t] = ssrc[e0+t];
  else if (t < 128) dstl[t-64] = sdst[e0+t-64];
  __syncthreads();

  f32x4 acc[4][2];
  {
    // rbf (64x16, zero-pad to K=32) @ W1c
    bf16x8 a[4];
#pragma unroll
    for (int rt=0;rt<4;rt++){
      if (g < 2)
        a[rt] = *reinterpret_cast<const bf16x8*>(rbfp + (size_t)(e0+rt*16+m)*NRBF + g*8);
      else {
        bf16x8 z;
#pragma unroll
        for (int e=0;e<8;e++) z[e]=0;
        a[rt]=z;
      }
    }
#pragma unroll
    for (int c=0;c<2;c++){
      bf16x8 b = *reinterpret_cast<const bf16x8*>(W1cp + ((size_t)(w*2+c)*64 + lane)*8);
      f32x4 z; z[0]=0.f; z[1]=0.f; z[2]=0.f; z[3]=0.f;
#pragma unroll
      for (int rt=0;rt<4;rt++)
        acc[rt][c] = __builtin_amdgcn_mfma_f32_16x16x32_bf16(a[rt], b, z, 0,0,0);
    }
  }
  // gather-add hA[src] (includes b1) + hB[dst], fp32 (round-3 numerics)
#pragma unroll
  for (int rt=0;rt<4;rt++){
#pragma unroll
    for (int r=0;r<4;r++){
      int row = rt*16 + g*4 + r;
      int s = srcl[row], d = dstl[row];
#pragma unroll
      for (int c=0;c<2;c++){
        int col = (w*2+c)*16 + m;
        acc[rt][c][r] += hA[(size_t)s*DH + col] + hB[(size_t)d*DH + col];
      }
    }
  }
  // relu -> swizzled X
  {
    char* Xc = (char*)X;
#pragma unroll
    for (int rt=0;rt<4;rt++){
#pragma unroll
      for (int c=0;c<2;c++){
        int col = (w*2+c)*16 + m;
#pragma unroll
        for (int r=0;r<4;r++){
          int row = rt*16 + g*4 + r;
          float y = fmaxf(acc[rt][c][r], 0.f);
          *reinterpret_cast<short*>(Xc + row*256 + ((col*2) ^ ((row&7)<<4))) = (short)f2b(y);
        }
      }
    }
  }
  __syncthreads();

  f32x4 acc2[4][2]; zero_acc(acc2);
  gemm_sw<256,4>(X, W2p, t, acc2);
  __syncthreads();   // all waves done reading X; reuse X for bf16 m

  float b2v0=b2[w*32+m], b2v1=b2[w*32+16+m];
  {
    char* Xc = (char*)X;
#pragma unroll
    for (int rt=0;rt<4;rt++){
#pragma unroll
      for (int c=0;c<2;c++){
        float bb = c? b2v1 : b2v0;
        int col = (w*2+c)*16 + m;
#pragma unroll
        for (int r=0;r<4;r++){
          int row = rt*16 + g*4 + r;
          *reinterpret_cast<short*>(Xc + row*256 + ((col*2) ^ ((row&7)<<4))) =
              (short)f2b(acc2[rt][c][r] + bb);
        }
      }
    }
  }
  __syncthreads();

  // segmented reduction over sorted dst runs; wave-uniform walk, one atomic
  // per (run x column). threads: col = t&127, half = t>>7 (rows 0-31 / 32-63).
  {
    const char* Xc = (const char*)X;
    int col = t & 127, half = t >> 7;
    int r0 = half*32, r1 = r0 + 32;
    float s = 0.f;
    int cur = dstl[r0];
    for (int row=r0; row<r1; row++){
      int d = dstl[row];
      if (d != cur){
        atomicAdd(&agg[(size_t)cur*DH + col], s);
        s = 0.f; cur = d;
      }
      s += b2f(*reinterpret_cast<const unsigned short*>(
               Xc + row*256 + ((col*2) ^ ((row&7)<<4))));
    }
    atomicAdd(&agg[(size_t)cur*DH + col], s);
  }
}

// Update MLP: u_in=[h, agg] (K=256), residual add. X reused for Y (LDS 32KB).
__global__ __launch_bounds__(256, 2) void upd_kernel(
    const short* __restrict__ hbfin, const float* __restrict__ agg,
    const short* __restrict__ W1p, const float* __restrict__ b1,
    const short* __restrict__ W2p, const float* __restrict__ b2,
    float* __restrict__ h, short* __restrict__ hbfout)
{
  __shared__ __align__(16) short X[64*256];
  const int t = threadIdx.x;
  const int n0 = blockIdx.x*64;
  char* Xc = (char*)X;
#pragma unroll
  for (int j=0;j<4;j++){
    int slot = j*256 + t;
    int lane16 = slot & 15, row = slot >> 4;
    int n = n0 + row;
    int nc = n < NN ? n : NN-1;
    bf16x8 v = *reinterpret_cast<const bf16x8*>(hbfin + (size_t)nc*DH + lane16*8);
    *reinterpret_cast<bf16x8*>(Xc + row*512 + ((lane16*16) ^ ((row&7)<<4))) = v;
    const float* ap = agg + (size_t)nc*DH + lane16*8;
    bf16x8 o;
#pragma unroll
    for (int e=0;e<8;e++) o[e] = (short)f2b(ap[e]);
    *reinterpret_cast<bf16x8*>(Xc + row*512 + ((256 + lane16*16) ^ ((row&7)<<4))) = o;
  }
  __syncthreads();

  f32x4 acc[4][2]; zero_acc(acc);
  gemm_sw<512,8>(X, W1p, t, acc);
  __syncthreads();   // all waves done reading X before Y overwrites it

  const int lane=t&63, w=t>>6, m=lane&15, g=lane>>4;
  float b1v0=b1[w*32+m], b1v1=b1[w*32+16+m];
#pragma unroll
  for (int rt=0;rt<4;rt++){
#pragma unroll
    for (int c=0;c<2;c++){
      float bb = c? b1v1 : b1v0;
      int col = (w*2+c)*16 + m;
#pragma unroll
      for (int r=0;r<4;r++){
        int row = rt*16 + g*4 + r;
        float y = fmaxf(acc[rt][c][r] + bb, 0.f);
        *reinterpret_cast<short*>(Xc + row*256 + ((col*2) ^ ((row&7)<<4))) = (short)f2b(y);
      }
    }
  }
  __syncthreads();

  f32x4 acc2[4][2]; zero_acc(acc2);
  gemm_sw<256,4>(X, W2p, t, acc2);

  float b2v0=b2[w*32+m], b2v1=b2[w*32+16+m];
#pragma unroll
  for (int rt=0;rt<4;rt++){
#pragma unroll
    for (int c=0;c<2;c++){
      float bb = c? b2v1 : b2v0;
      int col = (w*2+c)*16 + m;
#pragma unroll
      for (int r=0;r<4;r++){
        int row = rt*16 + g*4 + r;
        int n = n0 + row;
        if (n < NN){
          float val = h[(size_t)n*DH + col] + acc2[rt][c][r] + bb;
          h[(size_t)n*DH + col] = val;
          hbfout[(size_t)n*DH + col] = (short)f2b(val);
        }
      }
    }
  }
}

// Head on u-sorted pairs: logits = relu(hU[u]+hV[v]+rc*w1r).W2 + b2.
// Sorted u -> hU rows L1/L2-hot; scattered 4B output write via sidx.
__global__ __launch_bounds__(256, 2) void head_kernel(
    const float* __restrict__ hU, const float* __restrict__ hV,
    const float* __restrict__ coords,
    const int* __restrict__ su, const int* __restrict__ sv,
    const int* __restrict__ sidx,
    const float* __restrict__ w1r, const float* __restrict__ W2,
    const float* __restrict__ b2, float* __restrict__ out)
{
  const int t = threadIdx.x;
  const int l = t & 31;
  long p = (long)blockIdx.x*8 + (t>>5);
  int u = su[p], v = sv[p];
  float dx = coords[2*u]-coords[2*v], dy = coords[2*u+1]-coords[2*v+1];
  float rc = sqrtf(dx*dx + dy*dy + 1e-8f);
  f32x4 a  = *reinterpret_cast<const f32x4*>(hU + (size_t)u*DH + l*4);
  f32x4 bb = *reinterpret_cast<const f32x4*>(hV + (size_t)v*DH + l*4);
  f32x4 wr = *reinterpret_cast<const f32x4*>(w1r + l*4);
  f32x4 w2 = *reinterpret_cast<const f32x4*>(W2 + l*4);
  float s = 0.f;
#pragma unroll
  for (int i=0;i<4;i++){
    float y = fmaxf(a[i] + bb[i] + rc*wr[i], 0.f);
    s += y * w2[i];
  }
#pragma unroll
  for (int off=1; off<32; off<<=1)
    s += __shfl_xor(s, off, 32);
  if (l == 0) out[sidx[p]] = s + b2[0];
}

extern "C" void kernel_launch(void* const* d_in, const int* in_sizes, int n_in,
                              void* d_out, int out_size, void* d_ws, size_t ws_size,
                              hipStream_t stream)
{
  const float* coords  = (const float*)d_in[0];
  const int*   eidx    = (const int*)d_in[1];
  const int*   pairs   = (const int*)d_in[2];
  const float* node_W1 = (const float*)d_in[3];
  const float* node_b1 = (const float*)d_in[4];
  const float* node_W2 = (const float*)d_in[5];
  const float* node_b2 = (const float*)d_in[6];
  const float* msg_W1  = (const float*)d_in[7];
  const float* msg_b1  = (const float*)d_in[8];
  const float* msg_W2  = (const float*)d_in[9];
  const float* msg_b2  = (const float*)d_in[10];
  const float* upd_W1  = (const float*)d_in[11];
  const float* upd_b1  = (const float*)d_in[12];
  const float* upd_W2  = (const float*)d_in[13];
  const float* upd_b2  = (const float*)d_in[14];
  const float* head_W1 = (const float*)d_in[15];
  const float* head_b1 = (const float*)d_in[16];
  const float* head_W2 = (const float*)d_in[17];
  const float* head_b2 = (const float*)d_in[18];

  char* ws = (char*)d_ws;
  size_t off = 0;
  auto alloc = [&](size_t bytes)->void*{ void* p = ws + off; off += (bytes + 255) & ~(size_t)255; return p; };
  float* h      = (float*)alloc((size_t)NN*DH*4);
  short* hbf    = (short*)alloc((size_t)NN*DH*2);
  short* rbfp   = (short*)alloc((size_t)NE*NRBF*2);   // reused as sidx (pairs)
  float* hA     = (float*)alloc((size_t)NN*DH*4);     // reused for head hU
  float* hB     = (float*)alloc((size_t)NN*DH*4);     // reused for head hV
  float* agg    = (float*)alloc((size_t)NN*DH*4);
  int*   ssrc   = (int*)alloc((size_t)NE*4);          // reused as su (pairs)
  int*   sdst   = (int*)alloc((size_t)NE*4);          // reused as sv (pairs)
  int*   cnt    = (int*)alloc((size_t)NN*4);
  int*   rowptr = (int*)alloc((size_t)(NN+1)*4);
  int*   ofs    = (int*)alloc((size_t)NN*4);
  short* msgW1ap= (short*)alloc((size_t)NL*4*4096*2);
  short* msgW1bp= (short*)alloc((size_t)NL*4*4096*2);
  short* msgW1cp= (short*)alloc((size_t)NL*1*4096*2);
  short* msgW2p = (short*)alloc((size_t)NL*4*4096*2);
  short* updW1p = (short*)alloc((size_t)NL*8*4096*2);
  short* updW2p = (short*)alloc((size_t)NL*4*4096*2);
  short* headUp = (short*)alloc((size_t)4*4096*2);
  short* headVp = (short*)alloc((size_t)4*4096*2);
  short* nodeW2p= (short*)alloc((size_t)4*4096*2);

  const int* srcI = eidx;
  const int* dstI = eidx + NE;

  // ---- counting sort of edges by dst ----
  hipMemsetAsync(cnt, 0, (size_t)NN*4, stream);
  hist_kernel<<<(NE+255)/256, 256, 0, stream>>>(dstI, 1, NE, cnt);
  scan_kernel<<<1, 1024, 0, stream>>>(cnt, NE, rowptr);
  hipMemcpyAsync(ofs, rowptr, (size_t)NN*4, hipMemcpyDeviceToDevice, stream);
  scatter_kernel<<<(NE+255)/256, 256, 0, stream>>>(srcI, dstI, ofs, ssrc, sdst);

  rbf_kernel<<<(NE+255)/256, 256, 0, stream>>>(coords, ssrc, sdst, rbfp);

  // ---- weight packing (per-layer batched via blockIdx.y) ----
  {
    dim3 g4((8*4*64+255)/256, NL), g1((8*1*64+255)/256, NL), g8((8*8*64+255)/256, NL);
    pack_w_kernel<<<g4, 256, 0, stream>>>(msg_W1,          128, 4, (long)272*DH, 4*4096, msgW1ap);
    pack_w_kernel<<<g4, 256, 0, stream>>>(msg_W1 + 128*DH, 128, 4, (long)272*DH, 4*4096, msgW1bp);
    pack_w_kernel<<<g1, 256, 0, stream>>>(msg_W1 + 256*DH,  16, 1, (long)272*DH, 1*4096, msgW1cp);
    pack_w_kernel<<<g4, 256, 0, stream>>>(msg_W2, 128, 4, (long)DH*DH, 4*4096, msgW2p);
    pack_w_kernel<<<g8, 256, 0, stream>>>(upd_W1, 256, 8, (long)256*DH, 8*4096, updW1p);
    pack_w_kernel<<<g4, 256, 0, stream>>>(upd_W2, 128, 4, (long)DH*DH, 4*4096, updW2p);
    dim3 s4((8*4*64+255)/256, 1);
    pack_w_kernel<<<s4, 256, 0, stream>>>(head_W1,          128, 4, 0, 0, headUp);
    pack_w_kernel<<<s4, 256, 0, stream>>>(head_W1 + 128*DH, 128, 4, 0, 0, headVp);
    pack_w_kernel<<<s4, 256, 0, stream>>>(node_W2, 128, 4, 0, 0, nodeW2p);
  }

  node_kernel<<<(NN+63)/64, 256, 0, stream>>>(coords, node_W1, node_b1, nodeW2p, node_b2, h, hbf);

  const int NB = (NN+63)/64;
  for (int l=0; l<NL; l++){
    nodegemm2_f32<<<NB, 256, 0, stream>>>(hbf,
        msgW1ap + (size_t)l*4*4096, msg_b1 + l*DH, hA,
        msgW1bp + (size_t)l*4*4096, hB);
    hipMemsetAsync(agg, 0, (size_t)NN*DH*4, stream);
    msg_kernel<<<NE/64, 256, 0, stream>>>(hA, hB, rbfp, ssrc, sdst,
        msgW1cp + (size_t)l*1*4096, msgW2p + (size_t)l*4*4096, msg_b2 + l*DH, agg);
    upd_kernel<<<NB, 256, 0, stream>>>(hbf, agg,
        updW1p + (size_t)l*8*4096, upd_b1 + l*DH,
        updW2p + (size_t)l*4*4096, upd_b2 + l*DH, h, hbf);
  }

  // ---- counting sort of pairs by u (reuses cnt/rowptr/ofs; ssrc/sdst/rbfp free now) ----
  int* su   = ssrc;
  int* sv   = sdst;
  int* sidx = (int*)rbfp;
  hipMemsetAsync(cnt, 0, (size_t)NN*4, stream);
  hist_kernel<<<(NP+255)/256, 256, 0, stream>>>(pairs, 2, NP, cnt);
  scan_kernel<<<1, 1024, 0, stream>>>(cnt, NP, rowptr);
  hipMemcpyAsync(ofs, rowptr, (size_t)NN*4, hipMemcpyDeviceToDevice, stream);
  pair_scatter_kernel<<<(NP+255)/256, 256, 0, stream>>>(pairs, ofs, su, sv, sidx);

  // head reuses hA/hB buffers (free after last msg layer)
  nodegemm2_f32<<<NB, 256, 0, stream>>>(hbf, headUp, head_b1, hA, headVp, hB);
  head_kernel<<<NP/8, 256, 0, stream>>>(hA, hB, coords, su, sv, sidx,
      head_W1 + 256*DH, head_W2, head_b2, (float*)d_out);
}

// Round 14
// 942.170 us; speedup vs baseline: 1.1920x; 1.1920x over previous
//
#include <hip/hip_runtime.h>
#include <hip/hip_bf16.h>

#define NN 50000
#define NE 600000
#define NP 500000
#define DH 128
#define NRBF 16
#define NL 3

typedef __attribute__((ext_vector_type(8))) short bf16x8;
typedef __attribute__((ext_vector_type(4))) float f32x4;

__device__ __forceinline__ unsigned short f2b(float f){
  unsigned int u = __float_as_uint(f);
  u += 0x7fffu + ((u >> 16) & 1u);
  return (unsigned short)(u >> 16);
}
__device__ __forceinline__ float b2f(unsigned short u){
  return __uint_as_float(((unsigned)u) << 16);
}

__device__ __forceinline__ void zero_acc(f32x4 (&acc)[4][2]){
#pragma unroll
  for (int i=0;i<4;i++)
#pragma unroll
    for (int j=0;j<2;j++)
#pragma unroll
      for (int r=0;r<4;r++) acc[i][j][r]=0.f;
}

// Swizzled-LDS GEMM: X rows are RSB bytes (pow2), byte-in-row XOR'ed with
// ((row&7)<<4) (T2). Bp: packed weights [ct(8)][kb(KB)][lane(64)][e(8)] bf16.
template<int RSB, int KB>
__device__ __forceinline__ void gemm_sw(const short* X, const short* __restrict__ Bp,
                                        int t, f32x4 (&acc)[4][2]){
  const int lane=t&63, w=t>>6, m=lane&15, g=lane>>4;
  const char* Xc = (const char*)X;
#pragma unroll
  for (int kb=0; kb<KB; kb++){
    bf16x8 a[4];
#pragma unroll
    for (int rt=0; rt<4; rt++){
      int ar = rt*16 + m;
      a[rt] = *reinterpret_cast<const bf16x8*>(Xc + ar*RSB + ((kb*64 + g*16) ^ ((ar&7)<<4)));
    }
#pragma unroll
    for (int c=0;c<2;c++){
      bf16x8 b = *reinterpret_cast<const bf16x8*>(Bp + ((size_t)((w*2+c)*KB+kb)*64 + lane)*8);
#pragma unroll
      for (int rt=0; rt<4; rt++)
        acc[rt][c] = __builtin_amdgcn_mfma_f32_16x16x32_bf16(a[rt], b, acc[rt][c], 0,0,0);
    }
  }
}

// Pack W (Kr x 128 row-major fp32, zero-padded to KB*32 rows) into B-frag layout.
__global__ void pack_w_kernel(const float* __restrict__ W0, int Kr, int KB,
                              long wStride, long oStride, short* __restrict__ out0){
  int l = blockIdx.y;
  const float* W = W0 + (size_t)l*wStride;
  short* out = out0 + (size_t)l*oStride;
  int idx = blockIdx.x*256 + threadIdx.x;
  int total = 8*KB*64;
  if (idx >= total) return;
  int lane = idx & 63;
  int kb = (idx>>6) % KB;
  int ct = (idx>>6) / KB;
  int col = ct*16 + (lane&15);
  int k0 = kb*32 + 8*(lane>>4);
  bf16x8 pv;
#pragma unroll
  for (int e=0;e<8;e++){
    int k = k0+e;
    float f = (k<Kr) ? W[(size_t)k*DH + col] : 0.f;
    pv[e] = (short)f2b(f);
  }
  *reinterpret_cast<bf16x8*>(out + (size_t)idx*8) = pv;
}

// ---------- counting sort machinery ----------
__global__ void hist_kernel(const int* __restrict__ keys, int stride, int n,
                            int* __restrict__ cnt){
  int e = blockIdx.x*256 + threadIdx.x;
  if (e < n) atomicAdd(&cnt[keys[(size_t)e*stride]], 1);
}

__global__ void scan_kernel(const int* __restrict__ cnt, int total, int* __restrict__ rowptr){
  __shared__ int parts[1024];
  const int t = threadIdx.x;
  const int CH = (NN + 1023)/1024;  // 49
  int base = t*CH;
  int s = 0;
  for (int i=0;i<CH;i++){ int j=base+i; if (j<NN) s += cnt[j]; }
  parts[t] = s; __syncthreads();
  for (int off=1; off<1024; off<<=1){
    int v = (t>=off) ? parts[t-off] : 0;
    __syncthreads();
    parts[t] += v;
    __syncthreads();
  }
  int ex = (t==0) ? 0 : parts[t-1];
  for (int i=0;i<CH;i++){
    int j=base+i;
    if (j<NN){ rowptr[j] = ex; ex += cnt[j]; }
  }
  if (t==0) rowptr[NN] = total;
}

__global__ void scatter_kernel(const int* __restrict__ srcI, const int* __restrict__ dstI,
                               int* __restrict__ ofs, int* __restrict__ ssrc,
                               int* __restrict__ sdst){
  int e = blockIdx.x*256 + threadIdx.x;
  if (e >= NE) return;
  int d = dstI[e];
  int p = atomicAdd(&ofs[d], 1);
  ssrc[p] = srcI[e];
  sdst[p] = d;
}

// sort pairs by u; keep original index for scattered output write
__global__ void pair_scatter_kernel(const int* __restrict__ pairs, int* __restrict__ ofs,
                                    int* __restrict__ su, int* __restrict__ sv,
                                    int* __restrict__ sidx){
  int p = blockIdx.x*256 + threadIdx.x;
  if (p >= NP) return;
  int u = pairs[2*p], v = pairs[2*p+1];
  int pos = atomicAdd(&ofs[u], 1);
  su[pos] = u; sv[pos] = v; sidx[pos] = p;
}

__global__ void rbf_kernel(const float* __restrict__ coords, const int* __restrict__ srcI,
                           const int* __restrict__ dstI, short* __restrict__ rbfp){
  int e = blockIdx.x*256 + threadIdx.x;
  if (e >= NE) return;
  int s = srcI[e], d = dstI[e];
  float dx = coords[2*s]-coords[2*d];
  float dy = coords[2*s+1]-coords[2*d+1];
  float r = sqrtf(dx*dx + dy*dy + 1e-8f);
  bf16x8 v0, v1;
#pragma unroll
  for (int i=0;i<8;i++){
    float t0 = (r - 0.1f*i)*10.f;
    v0[i] = (short)f2b(expf(-t0*t0));
    float t1 = (r - 0.1f*(i+8))*10.f;
    v1[i] = (short)f2b(expf(-t1*t1));
  }
  *reinterpret_cast<bf16x8*>(rbfp + (size_t)e*NRBF) = v0;
  *reinterpret_cast<bf16x8*>(rbfp + (size_t)e*NRBF + 8) = v1;
}

// Node MLP: y1 = relu(coords@W1+b1) scalar (K=2), then 128x128 GEMM via MFMA.
__global__ __launch_bounds__(256, 2) void node_kernel(
    const float* __restrict__ coords, const float* __restrict__ W1, const float* __restrict__ b1,
    const short* __restrict__ W2p, const float* __restrict__ b2,
    float* __restrict__ h, short* __restrict__ hbf)
{
  __shared__ __align__(16) short X[64*128];
  const int t = threadIdx.x;
  const int n0 = blockIdx.x*64;
  {
    int row = t >> 2;
    int n = n0 + row;
    float c0=0.f, c1=0.f;
    if (n < NN){ c0 = coords[2*n]; c1 = coords[2*n+1]; }
    char* Xc = (char*)X;
#pragma unroll
    for (int i=0;i<32;i++){
      int col = (t&3)*32 + i;
      float y = fmaxf(c0*W1[col] + c1*W1[DH+col] + b1[col], 0.f);
      *reinterpret_cast<short*>(Xc + row*256 + ((col*2) ^ ((row&7)<<4))) = (short)f2b(y);
    }
  }
  __syncthreads();
  f32x4 acc[4][2]; zero_acc(acc);
  gemm_sw<256,4>(X, W2p, t, acc);
  const int lane=t&63, w=t>>6, m=lane&15, g=lane>>4;
  float b2v0=b2[w*32+m], b2v1=b2[w*32+16+m];
#pragma unroll
  for (int rt=0;rt<4;rt++){
#pragma unroll
    for (int c=0;c<2;c++){
      float bb = c? b2v1 : b2v0;
      int col = (w*2+c)*16 + m;
#pragma unroll
      for (int r=0;r<4;r++){
        int row = rt*16 + g*4 + r;
        int n = n0 + row;
        if (n < NN){
          float val = acc[rt][c][r] + bb;
          h[(size_t)n*DH + col] = val;
          hbf[(size_t)n*DH + col] = (short)f2b(val);
        }
      }
    }
  }
}

// Dual 128x128 GEMM on hbf rows: outA = hbf@WpA (+biasA), outB = hbf@WpB. fp32 outs.
__global__ __launch_bounds__(256, 2) void nodegemm2_f32(
    const short* __restrict__ hbf,
    const short* __restrict__ WpA, const float* __restrict__ biasA, float* __restrict__ outA,
    const short* __restrict__ WpB, float* __restrict__ outB)
{
  const int t=threadIdx.x, lane=t&63, w=t>>6, m=lane&15, g=lane>>4;
  const int n0 = blockIdx.x*64;
  f32x4 accA[4][2], accB[4][2]; zero_acc(accA); zero_acc(accB);
#pragma unroll
  for (int kb=0;kb<4;kb++){
    bf16x8 a[4];
#pragma unroll
    for (int rt=0;rt<4;rt++){
      int n = n0 + rt*16 + m; if (n >= NN) n = NN-1;
      a[rt] = *reinterpret_cast<const bf16x8*>(hbf + (size_t)n*DH + kb*32 + g*8);
    }
#pragma unroll
    for (int c=0;c<2;c++){
      bf16x8 bA = *reinterpret_cast<const bf16x8*>(WpA + ((size_t)((w*2+c)*4+kb)*64 + lane)*8);
      bf16x8 bB = *reinterpret_cast<const bf16x8*>(WpB + ((size_t)((w*2+c)*4+kb)*64 + lane)*8);
#pragma unroll
      for (int rt=0;rt<4;rt++){
        accA[rt][c] = __builtin_amdgcn_mfma_f32_16x16x32_bf16(a[rt], bA, accA[rt][c], 0,0,0);
        accB[rt][c] = __builtin_amdgcn_mfma_f32_16x16x32_bf16(a[rt], bB, accB[rt][c], 0,0,0);
      }
    }
  }
#pragma unroll
  for (int rt=0;rt<4;rt++){
#pragma unroll
    for (int c=0;c<2;c++){
      int col = (w*2+c)*16 + m;
      float bb = biasA ? biasA[col] : 0.f;
#pragma unroll
      for (int r=0;r<4;r++){
        int n = n0 + rt*16 + g*4 + r;
        if (n < NN){
          outA[(size_t)n*DH + col] = accA[rt][c][r] + bb;
          outB[(size_t)n*DH + col] = accB[rt][c][r];
        }
      }
    }
  }
}

// Message on dst-sorted edges: y = relu(hA[src]+hB[dst]+rbf@W1c), m = y@W2+b2.
// m stored bf16 back into X (17 KB LDS), segmented reduction over sorted dst
// runs -> few fp32 atomics. launch_bounds(256,4): VGPR cap 128 -> NO spill
// (round 12's (256,6) capped VGPR at 40 -> 188 MB scratch spill traffic).
__global__ __launch_bounds__(256, 4) void msg_kernel(
    const float* __restrict__ hA, const float* __restrict__ hB,
    const short* __restrict__ rbfp,
    const int* __restrict__ ssrc, const int* __restrict__ sdst,
    const short* __restrict__ W1cp, const short* __restrict__ W2p,
    const float* __restrict__ b2, float* __restrict__ agg)
{
  __shared__ __align__(16) short X[64*128];   // 16 KB swizzled, reused Y -> m
  __shared__ int srcl[64], dstl[64];
  const int t=threadIdx.x, lane=t&63, w=t>>6, m=lane&15, g=lane>>4;
  const int e0 = blockIdx.x*64;
  if (t < 64) srcl[t] = ssrc[e0+t];
  else if (t < 128) dstl[t-64] = sdst[e0+t-64];
  __syncthreads();

  f32x4 acc[4][2];
  {
    // rbf (64x16, zero-pad to K=32) @ W1c
    bf16x8 a[4];
#pragma unroll
    for (int rt=0;rt<4;rt++){
      if (g < 2)
        a[rt] = *reinterpret_cast<const bf16x8*>(rbfp + (size_t)(e0+rt*16+m)*NRBF + g*8);
      else {
        bf16x8 z;
#pragma unroll
        for (int e=0;e<8;e++) z[e]=0;
        a[rt]=z;
      }
    }
#pragma unroll
    for (int c=0;c<2;c++){
      bf16x8 b = *reinterpret_cast<const bf16x8*>(W1cp + ((size_t)(w*2+c)*64 + lane)*8);
      f32x4 z; z[0]=0.f; z[1]=0.f; z[2]=0.f; z[3]=0.f;
#pragma unroll
      for (int rt=0;rt<4;rt++)
        acc[rt][c] = __builtin_amdgcn_mfma_f32_16x16x32_bf16(a[rt], b, z, 0,0,0);
    }
  }
  // gather-add hA[src] (includes b1) + hB[dst], fp32 (round-3 numerics)
#pragma unroll
  for (int rt=0;rt<4;rt++){
#pragma unroll
    for (int r=0;r<4;r++){
      int row = rt*16 + g*4 + r;
      int s = srcl[row], d = dstl[row];
#pragma unroll
      for (int c=0;c<2;c++){
        int col = (w*2+c)*16 + m;
        acc[rt][c][r] += hA[(size_t)s*DH + col] + hB[(size_t)d*DH + col];
      }
    }
  }
  // relu -> swizzled X
  {
    char* Xc = (char*)X;
#pragma unroll
    for (int rt=0;rt<4;rt++){
#pragma unroll
      for (int c=0;c<2;c++){
        int col = (w*2+c)*16 + m;
#pragma unroll
        for (int r=0;r<4;r++){
          int row = rt*16 + g*4 + r;
          float y = fmaxf(acc[rt][c][r], 0.f);
          *reinterpret_cast<short*>(Xc + row*256 + ((col*2) ^ ((row&7)<<4))) = (short)f2b(y);
        }
      }
    }
  }
  __syncthreads();

  f32x4 acc2[4][2]; zero_acc(acc2);
  gemm_sw<256,4>(X, W2p, t, acc2);
  __syncthreads();   // all waves done reading X; reuse X for bf16 m

  float b2v0=b2[w*32+m], b2v1=b2[w*32+16+m];
  {
    char* Xc = (char*)X;
#pragma unroll
    for (int rt=0;rt<4;rt++){
#pragma unroll
      for (int c=0;c<2;c++){
        float bb = c? b2v1 : b2v0;
        int col = (w*2+c)*16 + m;
#pragma unroll
        for (int r=0;r<4;r++){
          int row = rt*16 + g*4 + r;
          *reinterpret_cast<short*>(Xc + row*256 + ((col*2) ^ ((row&7)<<4))) =
              (short)f2b(acc2[rt][c][r] + bb);
        }
      }
    }
  }
  __syncthreads();

  // segmented reduction over sorted dst runs; wave-uniform walk, one atomic
  // per (run x column). threads: col = t&127, half = t>>7 (rows 0-31 / 32-63).
  {
    const char* Xc = (const char*)X;
    int col = t & 127, half = t >> 7;
    int r0 = half*32, r1 = r0 + 32;
    float s = 0.f;
    int cur = dstl[r0];
    for (int row=r0; row<r1; row++){
      int d = dstl[row];
      if (d != cur){
        atomicAdd(&agg[(size_t)cur*DH + col], s);
        s = 0.f; cur = d;
      }
      s += b2f(*reinterpret_cast<const unsigned short*>(
               Xc + row*256 + ((col*2) ^ ((row&7)<<4))));
    }
    atomicAdd(&agg[(size_t)cur*DH + col], s);
  }
}

// Update MLP: u_in=[h, agg] (K=256), residual add. X reused for Y (LDS 32KB).
__global__ __launch_bounds__(256, 2) void upd_kernel(
    const short* __restrict__ hbfin, const float* __restrict__ agg,
    const short* __restrict__ W1p, const float* __restrict__ b1,
    const short* __restrict__ W2p, const float* __restrict__ b2,
    float* __restrict__ h, short* __restrict__ hbfout)
{
  __shared__ __align__(16) short X[64*256];
  const int t = threadIdx.x;
  const int n0 = blockIdx.x*64;
  char* Xc = (char*)X;
#pragma unroll
  for (int j=0;j<4;j++){
    int slot = j*256 + t;
    int lane16 = slot & 15, row = slot >> 4;
    int n = n0 + row;
    int nc = n < NN ? n : NN-1;
    bf16x8 v = *reinterpret_cast<const bf16x8*>(hbfin + (size_t)nc*DH + lane16*8);
    *reinterpret_cast<bf16x8*>(Xc + row*512 + ((lane16*16) ^ ((row&7)<<4))) = v;
    const float* ap = agg + (size_t)nc*DH + lane16*8;
    bf16x8 o;
#pragma unroll
    for (int e=0;e<8;e++) o[e] = (short)f2b(ap[e]);
    *reinterpret_cast<bf16x8*>(Xc + row*512 + ((256 + lane16*16) ^ ((row&7)<<4))) = o;
  }
  __syncthreads();

  f32x4 acc[4][2]; zero_acc(acc);
  gemm_sw<512,8>(X, W1p, t, acc);
  __syncthreads();   // all waves done reading X before Y overwrites it

  const int lane=t&63, w=t>>6, m=lane&15, g=lane>>4;
  float b1v0=b1[w*32+m], b1v1=b1[w*32+16+m];
#pragma unroll
  for (int rt=0;rt<4;rt++){
#pragma unroll
    for (int c=0;c<2;c++){
      float bb = c? b1v1 : b1v0;
      int col = (w*2+c)*16 + m;
#pragma unroll
      for (int r=0;r<4;r++){
        int row = rt*16 + g*4 + r;
        float y = fmaxf(acc[rt][c][r] + bb, 0.f);
        *reinterpret_cast<short*>(Xc + row*256 + ((col*2) ^ ((row&7)<<4))) = (short)f2b(y);
      }
    }
  }
  __syncthreads();

  f32x4 acc2[4][2]; zero_acc(acc2);
  gemm_sw<256,4>(X, W2p, t, acc2);

  float b2v0=b2[w*32+m], b2v1=b2[w*32+16+m];
#pragma unroll
  for (int rt=0;rt<4;rt++){
#pragma unroll
    for (int c=0;c<2;c++){
      float bb = c? b2v1 : b2v0;
      int col = (w*2+c)*16 + m;
#pragma unroll
      for (int r=0;r<4;r++){
        int row = rt*16 + g*4 + r;
        int n = n0 + row;
        if (n < NN){
          float val = h[(size_t)n*DH + col] + acc2[rt][c][r] + bb;
          h[(size_t)n*DH + col] = val;
          hbfout[(size_t)n*DH + col] = (short)f2b(val);
        }
      }
    }
  }
}

// Head on u-sorted pairs: logits = relu(hU[u]+hV[v]+rc*w1r).W2 + b2.
// Sorted u -> hU rows L1/L2-hot; scattered 4B output write via sidx.
__global__ __launch_bounds__(256, 2) void head_kernel(
    const float* __restrict__ hU, const float* __restrict__ hV,
    const float* __restrict__ coords,
    const int* __restrict__ su, const int* __restrict__ sv,
    const int* __restrict__ sidx,
    const float* __restrict__ w1r, const float* __restrict__ W2,
    const float* __restrict__ b2, float* __restrict__ out)
{
  const int t = threadIdx.x;
  const int l = t & 31;
  long p = (long)blockIdx.x*8 + (t>>5);
  int u = su[p], v = sv[p];
  float dx = coords[2*u]-coords[2*v], dy = coords[2*u+1]-coords[2*v+1];
  float rc = sqrtf(dx*dx + dy*dy + 1e-8f);
  f32x4 a  = *reinterpret_cast<const f32x4*>(hU + (size_t)u*DH + l*4);
  f32x4 bb = *reinterpret_cast<const f32x4*>(hV + (size_t)v*DH + l*4);
  f32x4 wr = *reinterpret_cast<const f32x4*>(w1r + l*4);
  f32x4 w2 = *reinterpret_cast<const f32x4*>(W2 + l*4);
  float s = 0.f;
#pragma unroll
  for (int i=0;i<4;i++){
    float y = fmaxf(a[i] + bb[i] + rc*wr[i], 0.f);
    s += y * w2[i];
  }
#pragma unroll
  for (int off=1; off<32; off<<=1)
    s += __shfl_xor(s, off, 32);
  if (l == 0) out[sidx[p]] = s + b2[0];
}

extern "C" void kernel_launch(void* const* d_in, const int* in_sizes, int n_in,
                              void* d_out, int out_size, void* d_ws, size_t ws_size,
                              hipStream_t stream)
{
  const float* coords  = (const float*)d_in[0];
  const int*   eidx    = (const int*)d_in[1];
  const int*   pairs   = (const int*)d_in[2];
  const float* node_W1 = (const float*)d_in[3];
  const float* node_b1 = (const float*)d_in[4];
  const float* node_W2 = (const float*)d_in[5];
  const float* node_b2 = (const float*)d_in[6];
  const float* msg_W1  = (const float*)d_in[7];
  const float* msg_b1  = (const float*)d_in[8];
  const float* msg_W2  = (const float*)d_in[9];
  const float* msg_b2  = (const float*)d_in[10];
  const float* upd_W1  = (const float*)d_in[11];
  const float* upd_b1  = (const float*)d_in[12];
  const float* upd_W2  = (const float*)d_in[13];
  const float* upd_b2  = (const float*)d_in[14];
  const float* head_W1 = (const float*)d_in[15];
  const float* head_b1 = (const float*)d_in[16];
  const float* head_W2 = (const float*)d_in[17];
  const float* head_b2 = (const float*)d_in[18];

  char* ws = (char*)d_ws;
  size_t off = 0;
  auto alloc = [&](size_t bytes)->void*{ void* p = ws + off; off += (bytes + 255) & ~(size_t)255; return p; };
  float* h      = (float*)alloc((size_t)NN*DH*4);
  short* hbf    = (short*)alloc((size_t)NN*DH*2);
  short* rbfp   = (short*)alloc((size_t)NE*NRBF*2);   // reused as sidx (pairs)
  float* hA     = (float*)alloc((size_t)NN*DH*4);     // reused for head hU
  float* hB     = (float*)alloc((size_t)NN*DH*4);     // reused for head hV
  float* agg    = (float*)alloc((size_t)NN*DH*4);
  int*   ssrc   = (int*)alloc((size_t)NE*4);          // reused as su (pairs)
  int*   sdst   = (int*)alloc((size_t)NE*4);          // reused as sv (pairs)
  int*   cnt    = (int*)alloc((size_t)NN*4);
  int*   rowptr = (int*)alloc((size_t)(NN+1)*4);
  int*   ofs    = (int*)alloc((size_t)NN*4);
  short* msgW1ap= (short*)alloc((size_t)NL*4*4096*2);
  short* msgW1bp= (short*)alloc((size_t)NL*4*4096*2);
  short* msgW1cp= (short*)alloc((size_t)NL*1*4096*2);
  short* msgW2p = (short*)alloc((size_t)NL*4*4096*2);
  short* updW1p = (short*)alloc((size_t)NL*8*4096*2);
  short* updW2p = (short*)alloc((size_t)NL*4*4096*2);
  short* headUp = (short*)alloc((size_t)4*4096*2);
  short* headVp = (short*)alloc((size_t)4*4096*2);
  short* nodeW2p= (short*)alloc((size_t)4*4096*2);

  const int* srcI = eidx;
  const int* dstI = eidx + NE;

  // ---- counting sort of edges by dst ----
  hipMemsetAsync(cnt, 0, (size_t)NN*4, stream);
  hist_kernel<<<(NE+255)/256, 256, 0, stream>>>(dstI, 1, NE, cnt);
  scan_kernel<<<1, 1024, 0, stream>>>(cnt, NE, rowptr);
  hipMemcpyAsync(ofs, rowptr, (size_t)NN*4, hipMemcpyDeviceToDevice, stream);
  scatter_kernel<<<(NE+255)/256, 256, 0, stream>>>(srcI, dstI, ofs, ssrc, sdst);

  rbf_kernel<<<(NE+255)/256, 256, 0, stream>>>(coords, ssrc, sdst, rbfp);

  // ---- weight packing (per-layer batched via blockIdx.y) ----
  {
    dim3 g4((8*4*64+255)/256, NL), g1((8*1*64+255)/256, NL), g8((8*8*64+255)/256, NL);
    pack_w_kernel<<<g4, 256, 0, stream>>>(msg_W1,          128, 4, (long)272*DH, 4*4096, msgW1ap);
    pack_w_kernel<<<g4, 256, 0, stream>>>(msg_W1 + 128*DH, 128, 4, (long)272*DH, 4*4096, msgW1bp);
    pack_w_kernel<<<g1, 256, 0, stream>>>(msg_W1 + 256*DH,  16, 1, (long)272*DH, 1*4096, msgW1cp);
    pack_w_kernel<<<g4, 256, 0, stream>>>(msg_W2, 128, 4, (long)DH*DH, 4*4096, msgW2p);
    pack_w_kernel<<<g8, 256, 0, stream>>>(upd_W1, 256, 8, (long)256*DH, 8*4096, updW1p);
    pack_w_kernel<<<g4, 256, 0, stream>>>(upd_W2, 128, 4, (long)DH*DH, 4*4096, updW2p);
    dim3 s4((8*4*64+255)/256, 1);
    pack_w_kernel<<<s4, 256, 0, stream>>>(head_W1,          128, 4, 0, 0, headUp);
    pack_w_kernel<<<s4, 256, 0, stream>>>(head_W1 + 128*DH, 128, 4, 0, 0, headVp);
    pack_w_kernel<<<s4, 256, 0, stream>>>(node_W2, 128, 4, 0, 0, nodeW2p);
  }

  node_kernel<<<(NN+63)/64, 256, 0, stream>>>(coords, node_W1, node_b1, nodeW2p, node_b2, h, hbf);

  const int NB = (NN+63)/64;
  for (int l=0; l<NL; l++){
    nodegemm2_f32<<<NB, 256, 0, stream>>>(hbf,
        msgW1ap + (size_t)l*4*4096, msg_b1 + l*DH, hA,
        msgW1bp + (size_t)l*4*4096, hB);
    hipMemsetAsync(agg, 0, (size_t)NN*DH*4, stream);
    msg_kernel<<<NE/64, 256, 0, stream>>>(hA, hB, rbfp, ssrc, sdst,
        msgW1cp + (size_t)l*1*4096, msgW2p + (size_t)l*4*4096, msg_b2 + l*DH, agg);
    upd_kernel<<<NB, 256, 0, stream>>>(hbf, agg,
        updW1p + (size_t)l*8*4096, upd_b1 + l*DH,
        updW2p + (size_t)l*4*4096, upd_b2 + l*DH, h, hbf);
  }

  // ---- counting sort of pairs by u (reuses cnt/rowptr/ofs; ssrc/sdst/rbfp free now) ----
  int* su   = ssrc;
  int* sv   = sdst;
  int* sidx = (int*)rbfp;
  hipMemsetAsync(cnt, 0, (size_t)NN*4, stream);
  hist_kernel<<<(NP+255)/256, 256, 0, stream>>>(pairs, 2, NP, cnt);
  scan_kernel<<<1, 1024, 0, stream>>>(cnt, NP, rowptr);
  hipMemcpyAsync(ofs, rowptr, (size_t)NN*4, hipMemcpyDeviceToDevice, stream);
  pair_scatter_kernel<<<(NP+255)/256, 256, 0, stream>>>(pairs, ofs, su, sv, sidx);

  // head reuses hA/hB buffers (free after last msg layer)
  nodegemm2_f32<<<NB, 256, 0, stream>>>(hbf, headUp, head_b1, hA, headVp, hB);
  head_kernel<<<NP/8, 256, 0, stream>>>(hA, hB, coords, su, sv, sidx,
      head_W1 + 256*DH, head_W2, head_b2, (float*)d_out);
}

// Round 15
// 781.558 us; speedup vs baseline: 1.4370x; 1.2055x over previous
//
#include <hip/hip_runtime.h>
#include <hip/hip_bf16.h>

#define NN 50000
#define NE 600000
#define NP 500000
#define DH 128
#define NRBF 16
#define NL 3
#define SCAN_NBLK ((NN + 1023) / 1024)   // 49

typedef __attribute__((ext_vector_type(8))) short bf16x8;
typedef __attribute__((ext_vector_type(4))) float f32x4;

__device__ __forceinline__ unsigned short f2b(float f){
  unsigned int u = __float_as_uint(f);
  u += 0x7fffu + ((u >> 16) & 1u);
  return (unsigned short)(u >> 16);
}
__device__ __forceinline__ float b2f(unsigned short u){
  return __uint_as_float(((unsigned)u) << 16);
}

__device__ __forceinline__ void zero_acc(f32x4 (&acc)[4][2]){
#pragma unroll
  for (int i=0;i<4;i++)
#pragma unroll
    for (int j=0;j<2;j++)
#pragma unroll
      for (int r=0;r<4;r++) acc[i][j][r]=0.f;
}

// Swizzled-LDS GEMM: X rows are RSB bytes (pow2), byte-in-row XOR'ed with
// ((row&7)<<4) (T2). Bp: packed weights [ct(8)][kb(KB)][lane(64)][e(8)] bf16.
template<int RSB, int KB>
__device__ __forceinline__ void gemm_sw(const short* X, const short* __restrict__ Bp,
                                        int t, f32x4 (&acc)[4][2]){
  const int lane=t&63, w=t>>6, m=lane&15, g=lane>>4;
  const char* Xc = (const char*)X;
#pragma unroll
  for (int kb=0; kb<KB; kb++){
    bf16x8 a[4];
#pragma unroll
    for (int rt=0; rt<4; rt++){
      int ar = rt*16 + m;
      a[rt] = *reinterpret_cast<const bf16x8*>(Xc + ar*RSB + ((kb*64 + g*16) ^ ((ar&7)<<4)));
    }
#pragma unroll
    for (int c=0;c<2;c++){
      bf16x8 b = *reinterpret_cast<const bf16x8*>(Bp + ((size_t)((w*2+c)*KB+kb)*64 + lane)*8);
#pragma unroll
      for (int rt=0; rt<4; rt++)
        acc[rt][c] = __builtin_amdgcn_mfma_f32_16x16x32_bf16(a[rt], b, acc[rt][c], 0,0,0);
    }
  }
}

// Pack W (Kr x 128 row-major fp32, zero-padded to KB*32 rows) into B-frag layout.
__global__ void pack_w_kernel(const float* __restrict__ W0, int Kr, int KB,
                              long wStride, long oStride, short* __restrict__ out0){
  int l = blockIdx.y;
  const float* W = W0 + (size_t)l*wStride;
  short* out = out0 + (size_t)l*oStride;
  int idx = blockIdx.x*256 + threadIdx.x;
  int total = 8*KB*64;
  if (idx >= total) return;
  int lane = idx & 63;
  int kb = (idx>>6) % KB;
  int ct = (idx>>6) / KB;
  int col = ct*16 + (lane&15);
  int k0 = kb*32 + 8*(lane>>4);
  bf16x8 pv;
#pragma unroll
  for (int e=0;e<8;e++){
    int k = k0+e;
    float f = (k<Kr) ? W[(size_t)k*DH + col] : 0.f;
    pv[e] = (short)f2b(f);
  }
  *reinterpret_cast<bf16x8*>(out + (size_t)idx*8) = pv;
}

// ---------- counting sort machinery (coalesced 3-phase scan) ----------
__global__ void hist_kernel(const int* __restrict__ keys, int stride, int n,
                            int* __restrict__ cnt){
  int e = blockIdx.x*256 + threadIdx.x;
  if (e < n) atomicAdd(&cnt[keys[(size_t)e*stride]], 1);
}

// phase A: per-1024-block sums of cnt (coalesced)
__global__ void blocksum_kernel(const int* __restrict__ cnt, int* __restrict__ partial){
  __shared__ int red[1024];
  int t = threadIdx.x, i = blockIdx.x*1024 + t;
  red[t] = (i < NN) ? cnt[i] : 0;
  __syncthreads();
  for (int off=512; off>0; off>>=1){
    if (t < off) red[t] += red[t+off];
    __syncthreads();
  }
  if (t == 0) partial[blockIdx.x] = red[0];
}

// phase B: exclusive scan of the 49 block partials (tiny, serial)
__global__ void scanpartial_kernel(int* __restrict__ partial){
  if (threadIdx.x == 0){
    int s = 0;
    for (int b=0; b<SCAN_NBLK; b++){ int v = partial[b]; partial[b] = s; s += v; }
  }
}

// phase C: per-block LDS Hillis-Steele scan + block offset -> rowptr AND ofs
__global__ void scanfinal_kernel(const int* __restrict__ cnt, const int* __restrict__ partial,
                                 int total, int* __restrict__ rowptr, int* __restrict__ ofs){
  __shared__ int sc[1024];
  int t = threadIdx.x, i = blockIdx.x*1024 + t;
  int v = (i < NN) ? cnt[i] : 0;
  sc[t] = v;
  __syncthreads();
  for (int off=1; off<1024; off<<=1){
    int u = (t >= off) ? sc[t-off] : 0;
    __syncthreads();
    sc[t] += u;
    __syncthreads();
  }
  if (i < NN){
    int ex = partial[blockIdx.x] + sc[t] - v;
    rowptr[i] = ex;
    ofs[i] = ex;
  }
  if (blockIdx.x == 0 && t == 0) rowptr[NN] = total;
}

__global__ void scatter_kernel(const int* __restrict__ srcI, const int* __restrict__ dstI,
                               int* __restrict__ ofs, int* __restrict__ ssrc,
                               int* __restrict__ sdst){
  int e = blockIdx.x*256 + threadIdx.x;
  if (e >= NE) return;
  int d = dstI[e];
  int p = atomicAdd(&ofs[d], 1);
  ssrc[p] = srcI[e];
  sdst[p] = d;
}

// sort pairs by u; keep original index for scattered output write
__global__ void pair_scatter_kernel(const int* __restrict__ pairs, int* __restrict__ ofs,
                                    int* __restrict__ su, int* __restrict__ sv,
                                    int* __restrict__ sidx){
  int p = blockIdx.x*256 + threadIdx.x;
  if (p >= NP) return;
  int u = pairs[2*p], v = pairs[2*p+1];
  int pos = atomicAdd(&ofs[u], 1);
  su[pos] = u; sv[pos] = v; sidx[pos] = p;
}

__global__ void rbf_kernel(const float* __restrict__ coords, const int* __restrict__ srcI,
                           const int* __restrict__ dstI, short* __restrict__ rbfp){
  int e = blockIdx.x*256 + threadIdx.x;
  if (e >= NE) return;
  int s = srcI[e], d = dstI[e];
  float dx = coords[2*s]-coords[2*d];
  float dy = coords[2*s+1]-coords[2*d+1];
  float r = sqrtf(dx*dx + dy*dy + 1e-8f);
  bf16x8 v0, v1;
#pragma unroll
  for (int i=0;i<8;i++){
    float t0 = (r - 0.1f*i)*10.f;
    v0[i] = (short)f2b(expf(-t0*t0));
    float t1 = (r - 0.1f*(i+8))*10.f;
    v1[i] = (short)f2b(expf(-t1*t1));
  }
  *reinterpret_cast<bf16x8*>(rbfp + (size_t)e*NRBF) = v0;
  *reinterpret_cast<bf16x8*>(rbfp + (size_t)e*NRBF + 8) = v1;
}

// Node MLP: y1 = relu(coords@W1+b1) scalar (K=2), then 128x128 GEMM via MFMA.
__global__ __launch_bounds__(256, 2) void node_kernel(
    const float* __restrict__ coords, const float* __restrict__ W1, const float* __restrict__ b1,
    const short* __restrict__ W2p, const float* __restrict__ b2,
    float* __restrict__ h, short* __restrict__ hbf)
{
  __shared__ __align__(16) short X[64*128];
  const int t = threadIdx.x;
  const int n0 = blockIdx.x*64;
  {
    int row = t >> 2;
    int n = n0 + row;
    float c0=0.f, c1=0.f;
    if (n < NN){ c0 = coords[2*n]; c1 = coords[2*n+1]; }
    char* Xc = (char*)X;
#pragma unroll
    for (int i=0;i<32;i++){
      int col = (t&3)*32 + i;
      float y = fmaxf(c0*W1[col] + c1*W1[DH+col] + b1[col], 0.f);
      *reinterpret_cast<short*>(Xc + row*256 + ((col*2) ^ ((row&7)<<4))) = (short)f2b(y);
    }
  }
  __syncthreads();
  f32x4 acc[4][2]; zero_acc(acc);
  gemm_sw<256,4>(X, W2p, t, acc);
  const int lane=t&63, w=t>>6, m=lane&15, g=lane>>4;
  float b2v0=b2[w*32+m], b2v1=b2[w*32+16+m];
#pragma unroll
  for (int rt=0;rt<4;rt++){
#pragma unroll
    for (int c=0;c<2;c++){
      float bb = c? b2v1 : b2v0;
      int col = (w*2+c)*16 + m;
#pragma unroll
      for (int r=0;r<4;r++){
        int row = rt*16 + g*4 + r;
        int n = n0 + row;
        if (n < NN){
          float val = acc[rt][c][r] + bb;
          h[(size_t)n*DH + col] = val;
          hbf[(size_t)n*DH + col] = (short)f2b(val);
        }
      }
    }
  }
}

// Dual 128x128 GEMM on hbf rows: outA = hbf@WpA (+biasA), outB = hbf@WpB. fp32 outs.
__global__ __launch_bounds__(256, 2) void nodegemm2_f32(
    const short* __restrict__ hbf,
    const short* __restrict__ WpA, const float* __restrict__ biasA, float* __restrict__ outA,
    const short* __restrict__ WpB, float* __restrict__ outB)
{
  const int t=threadIdx.x, lane=t&63, w=t>>6, m=lane&15, g=lane>>4;
  const int n0 = blockIdx.x*64;
  f32x4 accA[4][2], accB[4][2]; zero_acc(accA); zero_acc(accB);
#pragma unroll
  for (int kb=0;kb<4;kb++){
    bf16x8 a[4];
#pragma unroll
    for (int rt=0;rt<4;rt++){
      int n = n0 + rt*16 + m; if (n >= NN) n = NN-1;
      a[rt] = *reinterpret_cast<const bf16x8*>(hbf + (size_t)n*DH + kb*32 + g*8);
    }
#pragma unroll
    for (int c=0;c<2;c++){
      bf16x8 bA = *reinterpret_cast<const bf16x8*>(WpA + ((size_t)((w*2+c)*4+kb)*64 + lane)*8);
      bf16x8 bB = *reinterpret_cast<const bf16x8*>(WpB + ((size_t)((w*2+c)*4+kb)*64 + lane)*8);
#pragma unroll
      for (int rt=0;rt<4;rt++){
        accA[rt][c] = __builtin_amdgcn_mfma_f32_16x16x32_bf16(a[rt], bA, accA[rt][c], 0,0,0);
        accB[rt][c] = __builtin_amdgcn_mfma_f32_16x16x32_bf16(a[rt], bB, accB[rt][c], 0,0,0);
      }
    }
  }
#pragma unroll
  for (int rt=0;rt<4;rt++){
#pragma unroll
    for (int c=0;c<2;c++){
      int col = (w*2+c)*16 + m;
      float bb = biasA ? biasA[col] : 0.f;
#pragma unroll
      for (int r=0;r<4;r++){
        int n = n0 + rt*16 + g*4 + r;
        if (n < NN){
          outA[(size_t)n*DH + col] = accA[rt][c][r] + bb;
          outB[(size_t)n*DH + col] = accB[rt][c][r];
        }
      }
    }
  }
}

// Message on dst-sorted edges: y = relu(hA[src]+hB[dst]+rbf@W1c), m = y@W2+b2.
// m stored bf16 back into X (17 KB LDS), segmented reduction over sorted dst
// runs -> few fp32 atomics. launch_bounds(256,4): VGPR cap 128 -> no spill.
__global__ __launch_bounds__(256, 4) void msg_kernel(
    const float* __restrict__ hA, const float* __restrict__ hB,
    const short* __restrict__ rbfp,
    const int* __restrict__ ssrc, const int* __restrict__ sdst,
    const short* __restrict__ W1cp, const short* __restrict__ W2p,
    const float* __restrict__ b2, float* __restrict__ agg)
{
  __shared__ __align__(16) short X[64*128];   // 16 KB swizzled, reused Y -> m
  __shared__ int srcl[64], dstl[64];
  const int t=threadIdx.x, lane=t&63, w=t>>6, m=lane&15, g=lane>>4;
  const int e0 = blockIdx.x*64;
  if (t < 64) srcl[t] = ssrc[e0+t];
  else if (t < 128) dstl[t-64] = sdst[e0+t-64];
  __syncthreads();

  f32x4 acc[4][2];
  {
    // rbf (64x16, zero-pad to K=32) @ W1c
    bf16x8 a[4];
#pragma unroll
    for (int rt=0;rt<4;rt++){
      if (g < 2)
        a[rt] = *reinterpret_cast<const bf16x8*>(rbfp + (size_t)(e0+rt*16+m)*NRBF + g*8);
      else {
        bf16x8 z;
#pragma unroll
        for (int e=0;e<8;e++) z[e]=0;
        a[rt]=z;
      }
    }
#pragma unroll
    for (int c=0;c<2;c++){
      bf16x8 b = *reinterpret_cast<const bf16x8*>(W1cp + ((size_t)(w*2+c)*64 + lane)*8);
      f32x4 z; z[0]=0.f; z[1]=0.f; z[2]=0.f; z[3]=0.f;
#pragma unroll
      for (int rt=0;rt<4;rt++)
        acc[rt][c] = __builtin_amdgcn_mfma_f32_16x16x32_bf16(a[rt], b, z, 0,0,0);
    }
  }
  // gather-add hA[src] (includes b1) + hB[dst], fp32 (round-3 numerics)
#pragma unroll
  for (int rt=0;rt<4;rt++){
#pragma unroll
    for (int r=0;r<4;r++){
      int row = rt*16 + g*4 + r;
      int s = srcl[row], d = dstl[row];
#pragma unroll
      for (int c=0;c<2;c++){
        int col = (w*2+c)*16 + m;
        acc[rt][c][r] += hA[(size_t)s*DH + col] + hB[(size_t)d*DH + col];
      }
    }
  }
  // relu -> swizzled X
  {
    char* Xc = (char*)X;
#pragma unroll
    for (int rt=0;rt<4;rt++){
#pragma unroll
      for (int c=0;c<2;c++){
        int col = (w*2+c)*16 + m;
#pragma unroll
        for (int r=0;r<4;r++){
          int row = rt*16 + g*4 + r;
          float y = fmaxf(acc[rt][c][r], 0.f);
          *reinterpret_cast<short*>(Xc + row*256 + ((col*2) ^ ((row&7)<<4))) = (short)f2b(y);
        }
      }
    }
  }
  __syncthreads();

  f32x4 acc2[4][2]; zero_acc(acc2);
  gemm_sw<256,4>(X, W2p, t, acc2);
  __syncthreads();   // all waves done reading X; reuse X for bf16 m

  float b2v0=b2[w*32+m], b2v1=b2[w*32+16+m];
  {
    char* Xc = (char*)X;
#pragma unroll
    for (int rt=0;rt<4;rt++){
#pragma unroll
      for (int c=0;c<2;c++){
        float bb = c? b2v1 : b2v0;
        int col = (w*2+c)*16 + m;
#pragma unroll
        for (int r=0;r<4;r++){
          int row = rt*16 + g*4 + r;
          *reinterpret_cast<short*>(Xc + row*256 + ((col*2) ^ ((row&7)<<4))) =
              (short)f2b(acc2[rt][c][r] + bb);
        }
      }
    }
  }
  __syncthreads();

  // segmented reduction over sorted dst runs; wave-uniform walk, one atomic
  // per (run x column). threads: col = t&127, half = t>>7 (rows 0-31 / 32-63).
  {
    const char* Xc = (const char*)X;
    int col = t & 127, half = t >> 7;
    int r0 = half*32, r1 = r0 + 32;
    float s = 0.f;
    int cur = dstl[r0];
    for (int row=r0; row<r1; row++){
      int d = dstl[row];
      if (d != cur){
        atomicAdd(&agg[(size_t)cur*DH + col], s);
        s = 0.f; cur = d;
      }
      s += b2f(*reinterpret_cast<const unsigned short*>(
               Xc + row*256 + ((col*2) ^ ((row&7)<<4))));
    }
    atomicAdd(&agg[(size_t)cur*DH + col], s);
  }
}

// Update MLP: u_in=[h, agg] (K=256), residual add. X reused for Y (LDS 32KB).
__global__ __launch_bounds__(256, 2) void upd_kernel(
    const short* __restrict__ hbfin, const float* __restrict__ agg,
    const short* __restrict__ W1p, const float* __restrict__ b1,
    const short* __restrict__ W2p, const float* __restrict__ b2,
    float* __restrict__ h, short* __restrict__ hbfout)
{
  __shared__ __align__(16) short X[64*256];
  const int t = threadIdx.x;
  const int n0 = blockIdx.x*64;
  char* Xc = (char*)X;
#pragma unroll
  for (int j=0;j<4;j++){
    int slot = j*256 + t;
    int lane16 = slot & 15, row = slot >> 4;
    int n = n0 + row;
    int nc = n < NN ? n : NN-1;
    bf16x8 v = *reinterpret_cast<const bf16x8*>(hbfin + (size_t)nc*DH + lane16*8);
    *reinterpret_cast<bf16x8*>(Xc + row*512 + ((lane16*16) ^ ((row&7)<<4))) = v;
    const float* ap = agg + (size_t)nc*DH + lane16*8;
    bf16x8 o;
#pragma unroll
    for (int e=0;e<8;e++) o[e] = (short)f2b(ap[e]);
    *reinterpret_cast<bf16x8*>(Xc + row*512 + ((256 + lane16*16) ^ ((row&7)<<4))) = o;
  }
  __syncthreads();

  f32x4 acc[4][2]; zero_acc(acc);
  gemm_sw<512,8>(X, W1p, t, acc);
  __syncthreads();   // all waves done reading X before Y overwrites it

  const int lane=t&63, w=t>>6, m=lane&15, g=lane>>4;
  float b1v0=b1[w*32+m], b1v1=b1[w*32+16+m];
#pragma unroll
  for (int rt=0;rt<4;rt++){
#pragma unroll
    for (int c=0;c<2;c++){
      float bb = c? b1v1 : b1v0;
      int col = (w*2+c)*16 + m;
#pragma unroll
      for (int r=0;r<4;r++){
        int row = rt*16 + g*4 + r;
        float y = fmaxf(acc[rt][c][r] + bb, 0.f);
        *reinterpret_cast<short*>(Xc + row*256 + ((col*2) ^ ((row&7)<<4))) = (short)f2b(y);
      }
    }
  }
  __syncthreads();

  f32x4 acc2[4][2]; zero_acc(acc2);
  gemm_sw<256,4>(X, W2p, t, acc2);

  float b2v0=b2[w*32+m], b2v1=b2[w*32+16+m];
#pragma unroll
  for (int rt=0;rt<4;rt++){
#pragma unroll
    for (int c=0;c<2;c++){
      float bb = c? b2v1 : b2v0;
      int col = (w*2+c)*16 + m;
#pragma unroll
      for (int r=0;r<4;r++){
        int row = rt*16 + g*4 + r;
        int n = n0 + row;
        if (n < NN){
          float val = h[(size_t)n*DH + col] + acc2[rt][c][r] + bb;
          h[(size_t)n*DH + col] = val;
          hbfout[(size_t)n*DH + col] = (short)f2b(val);
        }
      }
    }
  }
}

// Head on u-sorted pairs: logits = relu(hU[u]+hV[v]+rc*w1r).W2 + b2.
// Sorted u -> hU rows L1/L2-hot; scattered 4B output write via sidx.
__global__ __launch_bounds__(256, 2) void head_kernel(
    const float* __restrict__ hU, const float* __restrict__ hV,
    const float* __restrict__ coords,
    const int* __restrict__ su, const int* __restrict__ sv,
    const int* __restrict__ sidx,
    const float* __restrict__ w1r, const float* __restrict__ W2,
    const float* __restrict__ b2, float* __restrict__ out)
{
  const int t = threadIdx.x;
  const int l = t & 31;
  long p = (long)blockIdx.x*8 + (t>>5);
  int u = su[p], v = sv[p];
  float dx = coords[2*u]-coords[2*v], dy = coords[2*u+1]-coords[2*v+1];
  float rc = sqrtf(dx*dx + dy*dy + 1e-8f);
  f32x4 a  = *reinterpret_cast<const f32x4*>(hU + (size_t)u*DH + l*4);
  f32x4 bb = *reinterpret_cast<const f32x4*>(hV + (size_t)v*DH + l*4);
  f32x4 wr = *reinterpret_cast<const f32x4*>(w1r + l*4);
  f32x4 w2 = *reinterpret_cast<const f32x4*>(W2 + l*4);
  float s = 0.f;
#pragma unroll
  for (int i=0;i<4;i++){
    float y = fmaxf(a[i] + bb[i] + rc*wr[i], 0.f);
    s += y * w2[i];
  }
#pragma unroll
  for (int off=1; off<32; off<<=1)
    s += __shfl_xor(s, off, 32);
  if (l == 0) out[sidx[p]] = s + b2[0];
}

extern "C" void kernel_launch(void* const* d_in, const int* in_sizes, int n_in,
                              void* d_out, int out_size, void* d_ws, size_t ws_size,
                              hipStream_t stream)
{
  const float* coords  = (const float*)d_in[0];
  const int*   eidx    = (const int*)d_in[1];
  const int*   pairs   = (const int*)d_in[2];
  const float* node_W1 = (const float*)d_in[3];
  const float* node_b1 = (const float*)d_in[4];
  const float* node_W2 = (const float*)d_in[5];
  const float* node_b2 = (const float*)d_in[6];
  const float* msg_W1  = (const float*)d_in[7];
  const float* msg_b1  = (const float*)d_in[8];
  const float* msg_W2  = (const float*)d_in[9];
  const float* msg_b2  = (const float*)d_in[10];
  const float* upd_W1  = (const float*)d_in[11];
  const float* upd_b1  = (const float*)d_in[12];
  const float* upd_W2  = (const float*)d_in[13];
  const float* upd_b2  = (const float*)d_in[14];
  const float* head_W1 = (const float*)d_in[15];
  const float* head_b1 = (const float*)d_in[16];
  const float* head_W2 = (const float*)d_in[17];
  const float* head_b2 = (const float*)d_in[18];

  char* ws = (char*)d_ws;
  size_t off = 0;
  auto alloc = [&](size_t bytes)->void*{ void* p = ws + off; off += (bytes + 255) & ~(size_t)255; return p; };
  float* h      = (float*)alloc((size_t)NN*DH*4);
  short* hbf    = (short*)alloc((size_t)NN*DH*2);
  short* rbfp   = (short*)alloc((size_t)NE*NRBF*2);   // reused as sidx (pairs)
  float* hA     = (float*)alloc((size_t)NN*DH*4);     // reused for head hU
  float* hB     = (float*)alloc((size_t)NN*DH*4);     // reused for head hV
  float* agg    = (float*)alloc((size_t)NN*DH*4);
  int*   ssrc   = (int*)alloc((size_t)NE*4);          // reused as su (pairs)
  int*   sdst   = (int*)alloc((size_t)NE*4);          // reused as sv (pairs)
  int*   cnt    = (int*)alloc((size_t)NN*4);
  int*   rowptr = (int*)alloc((size_t)(NN+1)*4);
  int*   ofs    = (int*)alloc((size_t)NN*4);
  int*   partial= (int*)alloc((size_t)SCAN_NBLK*4);
  short* msgW1ap= (short*)alloc((size_t)NL*4*4096*2);
  short* msgW1bp= (short*)alloc((size_t)NL*4*4096*2);
  short* msgW1cp= (short*)alloc((size_t)NL*1*4096*2);
  short* msgW2p = (short*)alloc((size_t)NL*4*4096*2);
  short* updW1p = (short*)alloc((size_t)NL*8*4096*2);
  short* updW2p = (short*)alloc((size_t)NL*4*4096*2);
  short* headUp = (short*)alloc((size_t)4*4096*2);
  short* headVp = (short*)alloc((size_t)4*4096*2);
  short* nodeW2p= (short*)alloc((size_t)4*4096*2);

  const int* srcI = eidx;
  const int* dstI = eidx + NE;

  // ---- counting sort of edges by dst (coalesced 3-phase scan) ----
  hipMemsetAsync(cnt, 0, (size_t)NN*4, stream);
  hist_kernel<<<(NE+255)/256, 256, 0, stream>>>(dstI, 1, NE, cnt);
  blocksum_kernel<<<SCAN_NBLK, 1024, 0, stream>>>(cnt, partial);
  scanpartial_kernel<<<1, 64, 0, stream>>>(partial);
  scanfinal_kernel<<<SCAN_NBLK, 1024, 0, stream>>>(cnt, partial, NE, rowptr, ofs);
  scatter_kernel<<<(NE+255)/256, 256, 0, stream>>>(srcI, dstI, ofs, ssrc, sdst);

  rbf_kernel<<<(NE+255)/256, 256, 0, stream>>>(coords, ssrc, sdst, rbfp);

  // ---- weight packing (per-layer batched via blockIdx.y) ----
  {
    dim3 g4((8*4*64+255)/256, NL), g1((8*1*64+255)/256, NL), g8((8*8*64+255)/256, NL);
    pack_w_kernel<<<g4, 256, 0, stream>>>(msg_W1,          128, 4, (long)272*DH, 4*4096, msgW1ap);
    pack_w_kernel<<<g4, 256, 0, stream>>>(msg_W1 + 128*DH, 128, 4, (long)272*DH, 4*4096, msgW1bp);
    pack_w_kernel<<<g1, 256, 0, stream>>>(msg_W1 + 256*DH,  16, 1, (long)272*DH, 1*4096, msgW1cp);
    pack_w_kernel<<<g4, 256, 0, stream>>>(msg_W2, 128, 4, (long)DH*DH, 4*4096, msgW2p);
    pack_w_kernel<<<g8, 256, 0, stream>>>(upd_W1, 256, 8, (long)256*DH, 8*4096, updW1p);
    pack_w_kernel<<<g4, 256, 0, stream>>>(upd_W2, 128, 4, (long)DH*DH, 4*4096, updW2p);
    dim3 s4((8*4*64+255)/256, 1);
    pack_w_kernel<<<s4, 256, 0, stream>>>(head_W1,          128, 4, 0, 0, headUp);
    pack_w_kernel<<<s4, 256, 0, stream>>>(head_W1 + 128*DH, 128, 4, 0, 0, headVp);
    pack_w_kernel<<<s4, 256, 0, stream>>>(node_W2, 128, 4, 0, 0, nodeW2p);
  }

  node_kernel<<<(NN+63)/64, 256, 0, stream>>>(coords, node_W1, node_b1, nodeW2p, node_b2, h, hbf);

  const int NB = (NN+63)/64;
  for (int l=0; l<NL; l++){
    nodegemm2_f32<<<NB, 256, 0, stream>>>(hbf,
        msgW1ap + (size_t)l*4*4096, msg_b1 + l*DH, hA,
        msgW1bp + (size_t)l*4*4096, hB);
    hipMemsetAsync(agg, 0, (size_t)NN*DH*4, stream);
    msg_kernel<<<NE/64, 256, 0, stream>>>(hA, hB, rbfp, ssrc, sdst,
        msgW1cp + (size_t)l*1*4096, msgW2p + (size_t)l*4*4096, msg_b2 + l*DH, agg);
    upd_kernel<<<NB, 256, 0, stream>>>(hbf, agg,
        updW1p + (size_t)l*8*4096, upd_b1 + l*DH,
        updW2p + (size_t)l*4*4096, upd_b2 + l*DH, h, hbf);
  }

  // ---- counting sort of pairs by u (coalesced 3-phase scan) ----
  int* su   = ssrc;
  int* sv   = sdst;
  int* sidx = (int*)rbfp;
  hipMemsetAsync(cnt, 0, (size_t)NN*4, stream);
  hist_kernel<<<(NP+255)/256, 256, 0, stream>>>(pairs, 2, NP, cnt);
  blocksum_kernel<<<SCAN_NBLK, 1024, 0, stream>>>(cnt, partial);
  scanpartial_kernel<<<1, 64, 0, stream>>>(partial);
  scanfinal_kernel<<<SCAN_NBLK, 1024, 0, stream>>>(cnt, partial, NP, rowptr, ofs);
  pair_scatter_kernel<<<(NP+255)/256, 256, 0, stream>>>(pairs, ofs, su, sv, sidx);

  // head reuses hA/hB buffers (free after last msg layer)
  nodegemm2_f32<<<NB, 256, 0, stream>>>(hbf, headUp, head_b1, hA, headVp, hB);
  head_kernel<<<NP/8, 256, 0, stream>>>(hA, hB, coords, su, sv, sidx,
      head_W1 + 256*DH, head_W2, head_b2, (float*)d_out);
}